// Round 10
// baseline (473.124 us; speedup 1.0000x reference)
//
#include <hip/hip_runtime.h>
#include <hip/hip_bf16.h>

#define N_NODES 100000
#define N_EDGES 1600000
#define IN_F    32
#define D       128
#define OUT_F   16
#define NB      ((N_NODES + 255) / 256)   // 391 scan blocks
#define NSLICE  8
#define SLICE_NODES (N_NODES / NSLICE)    // 12500

// edge-scan geometry: 16 edges/thread via 4x int4 loads
#define NI4     (N_EDGES / 4)             // 400000 int4s
#define EBLK    ((NI4 + 1023) / 1024)     // 391 blocks per slice-group
#define NEMB    (N_NODES / 16)            // 6250 embed blocks
#define NCNT    (NSLICE * EBLK)           // 3128 count blocks
#define NWP     32                        // wprep blocks

typedef __attribute__((ext_vector_type(8))) short  bf16x8;
typedef __attribute__((ext_vector_type(4))) float  f32x4;

__device__ __forceinline__ unsigned short f2bf(float x) {     // RNE f32 -> bf16 bits
    unsigned u = __float_as_uint(x);
    unsigned r = (u + 0x7FFFu + ((u >> 16) & 1u)) >> 16;
    return (unsigned short)r;
}
__device__ __forceinline__ float bf2f(unsigned short h) {
    return __uint_as_float(((unsigned)h) << 16);
}

// ---------------------------------------------------------------------------
// Fused prologue: [0,NEMB) embed | [NEMB,NEMB+NCNT) count | rest wprep.
// All three are independent; one launch hides embed+wprep under count.
// ---------------------------------------------------------------------------
__global__ __launch_bounds__(256) void k_prep(const float* __restrict__ x,
                                              const float* __restrict__ Wemb,
                                              const float* __restrict__ bemb,
                                              unsigned short* __restrict__ h_hi,
                                              unsigned short* __restrict__ h_lo,
                                              const int* __restrict__ dst,
                                              int* __restrict__ cnt,
                                              const float* __restrict__ W1r,
                                              const float* __restrict__ W1o,
                                              const float* __restrict__ W2r,
                                              const float* __restrict__ W2o,
                                              unsigned short* __restrict__ wp) {
    const int bid = blockIdx.x;
    const int tid = threadIdx.x;

    if (bid < NEMB) {
        // ---------------- embed: 16 nodes/block ----------------
        __shared__ float xs[16][IN_F];
        const int base = bid * 16;
        if (tid < 128) {
            int r = tid >> 3, c4 = (tid & 7) << 2;
            *reinterpret_cast<float4*>(&xs[r][c4]) =
                *reinterpret_cast<const float4*>(x + (long)(base + r) * IN_F + c4);
        }
        __syncthreads();

        const int nl   = tid >> 4;
        const int col0 = (tid & 15) << 3;

        float acc[8];
        {
            float4 b0 = *reinterpret_cast<const float4*>(bemb + col0);
            float4 b1 = *reinterpret_cast<const float4*>(bemb + col0 + 4);
            acc[0] = b0.x; acc[1] = b0.y; acc[2] = b0.z; acc[3] = b0.w;
            acc[4] = b1.x; acc[5] = b1.y; acc[6] = b1.z; acc[7] = b1.w;
        }
#pragma unroll
        for (int k = 0; k < IN_F; ++k) {
            const float xv = xs[nl][k];
            float4 w0 = *reinterpret_cast<const float4*>(Wemb + k * D + col0);
            float4 w1 = *reinterpret_cast<const float4*>(Wemb + k * D + col0 + 4);
            acc[0] += xv * w0.x; acc[1] += xv * w0.y; acc[2] += xv * w0.z; acc[3] += xv * w0.w;
            acc[4] += xv * w1.x; acc[5] += xv * w1.y; acc[6] += xv * w1.z; acc[7] += xv * w1.w;
        }
        unsigned short hh[8], ll[8];
#pragma unroll
        for (int j = 0; j < 8; ++j) {
            unsigned short h = f2bf(acc[j]);
            hh[j] = h;
            ll[j] = f2bf(acc[j] - bf2f(h));
        }
        long off = (long)(base + nl) * D + col0;
        *reinterpret_cast<bf16x8*>(h_hi + off) = *reinterpret_cast<bf16x8*>(hh);
        *reinterpret_cast<bf16x8*>(h_lo + off) = *reinterpret_cast<bf16x8*>(ll);

    } else if (bid < NEMB + NCNT) {
        // ---------------- count: slice-gated, 4x int4 per thread ----------------
        const int cb    = bid - NEMB;
        const int slice = cb & (NSLICE - 1);
        const int chunk = cb >> 3;
        const int lo = slice * SLICE_NODES;
        const int hi = lo + SLICE_NODES;
        const int4* dst4 = reinterpret_cast<const int4*>(dst);
        const int i4base = chunk * 1024;

        int4 d[4];
        bool ok[4];
#pragma unroll
        for (int j = 0; j < 4; ++j) {
            int idx = i4base + j * 256 + tid;
            ok[j] = idx < NI4;
            if (ok[j]) d[j] = dst4[idx];
        }
#pragma unroll
        for (int j = 0; j < 4; ++j) {
            if (ok[j]) {
                if (d[j].x >= lo && d[j].x < hi) atomicAdd(&cnt[d[j].x], 1);
                if (d[j].y >= lo && d[j].y < hi) atomicAdd(&cnt[d[j].y], 1);
                if (d[j].z >= lo && d[j].z < hi) atomicAdd(&cnt[d[j].z], 1);
                if (d[j].w >= lo && d[j].w < hi) atomicAdd(&cnt[d[j].w], 1);
            }
        }

    } else {
        // ---------------- wprep: split-bf16 B-fragment pack ----------------
        int c = (bid - NEMB - NCNT) * 256 + tid;       // 0..8191
        int layer = c >> 12;
        int ko = (c >> 7) & 31;
        int n = c & 127;
        const float* Wrel  = layer ? W2r : W1r;
        const float* Wroot = layer ? W2o : W1o;

        unsigned short hi8[8], lo8[8];
#pragma unroll
        for (int j = 0; j < 8; ++j) {
            int k = ko * 8 + j;
            float w = (k < D) ? Wrel[k * D + n] : Wroot[(k - D) * D + n];
            unsigned short h = f2bf(w);
            hi8[j] = h;
            lo8[j] = f2bf(w - bf2f(h));
        }
        unsigned short* base = wp + layer * 65536 + ((ko * 128 + n) << 3);
        *reinterpret_cast<bf16x8*>(base)         = *reinterpret_cast<bf16x8*>(hi8);
        *reinterpret_cast<bf16x8*>(base + 32768) = *reinterpret_cast<bf16x8*>(lo8);
    }
}

// ---------------------------------------------------------------------------
// 3-kernel exclusive prefix scan of cnt[N_NODES] -> offsets (+ cursor copy)
// ---------------------------------------------------------------------------
__global__ __launch_bounds__(256) void k_scan1(const int* __restrict__ cnt,
                                               int* __restrict__ part,
                                               int* __restrict__ blockSums) {
    __shared__ int s[256];
    int i = blockIdx.x * 256 + threadIdx.x;
    int v = (i < N_NODES) ? cnt[i] : 0;
    s[threadIdx.x] = v;
    __syncthreads();
    for (int off = 1; off < 256; off <<= 1) {
        int x = (threadIdx.x >= off) ? s[threadIdx.x - off] : 0;
        __syncthreads();
        s[threadIdx.x] += x;
        __syncthreads();
    }
    if (i < N_NODES) part[i] = s[threadIdx.x] - v;
    if (threadIdx.x == 255) blockSums[blockIdx.x] = s[255];
}

__global__ __launch_bounds__(512) void k_scan2(int* __restrict__ blockSums) {
    __shared__ int s[512];
    int t = threadIdx.x;
    int v = (t < NB) ? blockSums[t] : 0;
    s[t] = v;
    __syncthreads();
    for (int off = 1; off < 512; off <<= 1) {
        int x = (t >= off) ? s[t - off] : 0;
        __syncthreads();
        s[t] += x;
        __syncthreads();
    }
    if (t < NB) blockSums[t] = s[t] - v;
}

__global__ __launch_bounds__(256) void k_scan3(int* __restrict__ offsets,
                                               const int* __restrict__ blockSums,
                                               int* __restrict__ cursor) {
    int i = blockIdx.x * 256 + threadIdx.x;
    if (i < N_NODES) {
        int o = offsets[i] + blockSums[blockIdx.x];
        offsets[i] = o;
        cursor[i]  = o;
    }
}

// ---------------------------------------------------------------------------
// fill CSR: csr[cursor[dst]++] = src — slice-gated, 4x int4 per thread.
// ---------------------------------------------------------------------------
__global__ __launch_bounds__(256) void k_fill(const int* __restrict__ src,
                                              const int* __restrict__ dst,
                                              int* __restrict__ cursor,
                                              int* __restrict__ csr) {
    const int slice = blockIdx.x & (NSLICE - 1);
    const int chunk = blockIdx.x >> 3;
    const int lo = slice * SLICE_NODES;
    const int hi = lo + SLICE_NODES;
    const int4* dst4 = reinterpret_cast<const int4*>(dst);
    const int4* src4 = reinterpret_cast<const int4*>(src);
    const int i4base = chunk * 1024;
    const int tid = threadIdx.x;

    int4 d[4], s[4];
    bool ok[4];
#pragma unroll
    for (int j = 0; j < 4; ++j) {
        int idx = i4base + j * 256 + tid;
        ok[j] = idx < NI4;
        if (ok[j]) { d[j] = dst4[idx]; s[j] = src4[idx]; }
    }
#pragma unroll
    for (int j = 0; j < 4; ++j) {
        if (ok[j]) {
            if (d[j].x >= lo && d[j].x < hi) { int p = atomicAdd(&cursor[d[j].x], 1); csr[p] = s[j].x; }
            if (d[j].y >= lo && d[j].y < hi) { int p = atomicAdd(&cursor[d[j].y], 1); csr[p] = s[j].y; }
            if (d[j].z >= lo && d[j].z < hi) { int p = atomicAdd(&cursor[d[j].z], 1); csr[p] = s[j].z; }
            if (d[j].w >= lo && d[j].w < hi) { int p = atomicAdd(&cursor[d[j].w], 1); csr[p] = s[j].w; }
        }
    }
}

// ---------------------------------------------------------------------------
// Fused RGCN layer, 512 threads / 32 nodes.
//   gather: one (node, col-chunk) per thread, software-pipelined 4-edge batch
//   stage : ko 16..31 root copy
//   MFMA  : 8 waves, K=256 split-bf16 (hh, lh, hl)
//   LAST=0: relu + split-write hout(hi/lo)
//   LAST=1: relu -> f32 h in LDS (bank-rotated) -> out = h @ W_out + b_out
// ---------------------------------------------------------------------------
template <bool LAST>
__global__ __launch_bounds__(512) void k_fused(const unsigned short* __restrict__ hin_hi,
                                               const unsigned short* __restrict__ hin_lo,
                                               const int* __restrict__ csr,
                                               const int* __restrict__ offsets,
                                               const int* __restrict__ cnt,
                                               const unsigned short* __restrict__ Wh,
                                               const unsigned short* __restrict__ Wl,
                                               const float* __restrict__ b,
                                               unsigned short* __restrict__ ho_hi,
                                               unsigned short* __restrict__ ho_lo,
                                               const float* __restrict__ Wout,
                                               const float* __restrict__ bout,
                                               float* __restrict__ outp) {
    __shared__ unsigned short Ahi[32 * 32 * 8];   // 16 KB: [ko][row][8] swizzled
    __shared__ unsigned short Alo[32 * 32 * 8];   // 16 KB
    const int base = blockIdx.x * 32;
    const int tid  = threadIdx.x;

    // ---- gather phase: ko = 0..15, one (node,chunk) per thread ----
    {
        const int ko  = tid & 15;
        const int q8  = ko << 3;
        const int row = tid >> 4;                 // 0..31
        const int node = base + row;
        const int beg = offsets[node];
        const int deg = cnt[node];
        const int end = beg + deg;

        float a0[8], a1[8];
#pragma unroll
        for (int j = 0; j < 8; ++j) { a0[j] = 0.f; a1[j] = 0.f; }

        int i = beg;
        const int stop = beg + (deg & ~3);
        if (i < stop) {
            // prologue: load batch 0
            int s0 = csr[i], s1 = csr[i + 1], s2 = csr[i + 2], s3 = csr[i + 3];
            bf16x8 p0 = *reinterpret_cast<const bf16x8*>(hin_hi + (long)s0 * D + q8);
            bf16x8 p1 = *reinterpret_cast<const bf16x8*>(hin_hi + (long)s1 * D + q8);
            bf16x8 p2 = *reinterpret_cast<const bf16x8*>(hin_hi + (long)s2 * D + q8);
            bf16x8 p3 = *reinterpret_cast<const bf16x8*>(hin_hi + (long)s3 * D + q8);
            i += 4;
            for (; i < stop; i += 4) {
                // issue next batch's loads before consuming previous
                int t0 = csr[i], t1 = csr[i + 1], t2 = csr[i + 2], t3 = csr[i + 3];
                bf16x8 n0 = *reinterpret_cast<const bf16x8*>(hin_hi + (long)t0 * D + q8);
                bf16x8 n1 = *reinterpret_cast<const bf16x8*>(hin_hi + (long)t1 * D + q8);
                bf16x8 n2 = *reinterpret_cast<const bf16x8*>(hin_hi + (long)t2 * D + q8);
                bf16x8 n3 = *reinterpret_cast<const bf16x8*>(hin_hi + (long)t3 * D + q8);
#pragma unroll
                for (int j = 0; j < 8; ++j) {
                    a0[j] += bf2f((unsigned short)p0[j]) + bf2f((unsigned short)p1[j]);
                    a1[j] += bf2f((unsigned short)p2[j]) + bf2f((unsigned short)p3[j]);
                }
                p0 = n0; p1 = n1; p2 = n2; p3 = n3;
            }
#pragma unroll
            for (int j = 0; j < 8; ++j) {
                a0[j] += bf2f((unsigned short)p0[j]) + bf2f((unsigned short)p1[j]);
                a1[j] += bf2f((unsigned short)p2[j]) + bf2f((unsigned short)p3[j]);
            }
        }
        for (; i < end; ++i) {
            int s0 = csr[i];
            bf16x8 v0 = *reinterpret_cast<const bf16x8*>(hin_hi + (long)s0 * D + q8);
#pragma unroll
            for (int j = 0; j < 8; ++j) a0[j] += bf2f((unsigned short)v0[j]);
        }

        const float sc = 1.f / fmaxf((float)deg, 1.f);
        unsigned short hh[8], ll[8];
#pragma unroll
        for (int j = 0; j < 8; ++j) {
            float v = (a0[j] + a1[j]) * sc;
            unsigned short h = f2bf(v);
            hh[j] = h;
            ll[j] = f2bf(v - bf2f(h));
        }
        const int byteoff = ((ko * 32 + row) * 16) ^ ((ko & 7) << 4);
        *reinterpret_cast<bf16x8*>(reinterpret_cast<char*>(Ahi) + byteoff) =
            *reinterpret_cast<bf16x8*>(hh);
        *reinterpret_cast<bf16x8*>(reinterpret_cast<char*>(Alo) + byteoff) =
            *reinterpret_cast<bf16x8*>(ll);
    }

    // ---- stage root rows: ko = 16..31 (pure copy, pre-split input) ----
    {
        int ko16 = tid & 15;
        int row  = tid >> 4;
        long off = (long)(base + row) * D + ko16 * 8;
        bf16x8 vh = *reinterpret_cast<const bf16x8*>(hin_hi + off);
        bf16x8 vl = *reinterpret_cast<const bf16x8*>(hin_lo + off);
        int ko = 16 + ko16;
        int byteoff = ((ko * 32 + row) * 16) ^ ((ko & 7) << 4);
        *reinterpret_cast<bf16x8*>(reinterpret_cast<char*>(Ahi) + byteoff) = vh;
        *reinterpret_cast<bf16x8*>(reinterpret_cast<char*>(Alo) + byteoff) = vl;
    }
    __syncthreads();

    // ---- MFMA: 8 waves, wave = (mw rows, nwq col-quarter) ----
    const int lane = tid & 63;
    const int wid  = tid >> 6;          // 0..7
    const int mw  = wid & 1;
    const int nwq = wid >> 1;           // 0..3
    const int l15 = lane & 15;
    const int l4  = lane >> 4;

    f32x4 acc[2];
#pragma unroll
    for (int ct = 0; ct < 2; ++ct) acc[ct] = (f32x4){0.f, 0.f, 0.f, 0.f};

    const int arow = mw * 16 + l15;

#pragma unroll
    for (int s = 0; s < 8; ++s) {
        const int ks = s * 4 + l4;
        const int abyte = ((ks * 32 + arow) * 16) ^ ((ks & 7) << 4);
        bf16x8 ah = *reinterpret_cast<const bf16x8*>(
                        reinterpret_cast<const char*>(Ahi) + abyte);
        bf16x8 al = *reinterpret_cast<const bf16x8*>(
                        reinterpret_cast<const char*>(Alo) + abyte);
#pragma unroll
        for (int ct = 0; ct < 2; ++ct) {
            const int colb = nwq * 32 + ct * 16 + l15;
            const long bidx = ((long)(ks * 128 + colb)) << 3;
            bf16x8 bh = *reinterpret_cast<const bf16x8*>(Wh + bidx);
            bf16x8 bl = *reinterpret_cast<const bf16x8*>(Wl + bidx);
            acc[ct] = __builtin_amdgcn_mfma_f32_16x16x32_bf16(ah, bh, acc[ct], 0, 0, 0);
            acc[ct] = __builtin_amdgcn_mfma_f32_16x16x32_bf16(al, bh, acc[ct], 0, 0, 0);
            acc[ct] = __builtin_amdgcn_mfma_f32_16x16x32_bf16(ah, bl, acc[ct], 0, 0, 0);
        }
    }

    if (!LAST) {
        // relu + split-write to global hout
#pragma unroll
        for (int ct = 0; ct < 2; ++ct) {
            const int col = nwq * 32 + ct * 16 + l15;
            const float bv = b[col];
#pragma unroll
            for (int r = 0; r < 4; ++r) {
                long node = base + mw * 16 + l4 * 4 + r;
                float v = fmaxf(acc[ct][r] + bv, 0.f);
                unsigned short h = f2bf(v);
                ho_hi[node * D + col] = h;
                ho_lo[node * D + col] = f2bf(v - bf2f(h));
            }
        }
    } else {
        // relu -> f32 h in LDS (bank-rotated by 4*node) -> projection to OUT
        __syncthreads();                       // all MFMA LDS reads complete
        float* hsm = reinterpret_cast<float*>(Ahi);   // 32 x 128 f32 = 16 KB
#pragma unroll
        for (int ct = 0; ct < 2; ++ct) {
            const int col = nwq * 32 + ct * 16 + l15;
            const float bv = b[col];
#pragma unroll
            for (int r = 0; r < 4; ++r) {
                int nl = mw * 16 + l4 * 4 + r;
                hsm[nl * D + ((col + 4 * nl) & 127)] = fmaxf(acc[ct][r] + bv, 0.f);
            }
        }
        __syncthreads();

        const int nl = tid >> 4;               // node 0..31
        const int oo = tid & 15;               // out col 0..15
        float acc0 = bout[oo];
#pragma unroll 8
        for (int k = 0; k < D; ++k) {
            float hv = hsm[nl * D + ((k + 4 * nl) & 127)];
            acc0 += hv * Wout[k * OUT_F + oo];
        }
        outp[(long)(base + nl) * OUT_F + oo] = acc0;
    }
}

// ---------------------------------------------------------------------------
extern "C" void kernel_launch(void* const* d_in, const int* in_sizes, int n_in,
                              void* d_out, int out_size, void* d_ws, size_t ws_size,
                              hipStream_t stream) {
    const float* x      = (const float*)d_in[0];
    const int*   edge   = (const int*)d_in[1];
    const float* W_emb  = (const float*)d_in[2];
    const float* b_emb  = (const float*)d_in[3];
    const float* W1_rel = (const float*)d_in[4];
    const float* W1_root= (const float*)d_in[5];
    const float* b1     = (const float*)d_in[6];
    const float* W2_rel = (const float*)d_in[7];
    const float* W2_root= (const float*)d_in[8];
    const float* b2     = (const float*)d_in[9];
    const float* W_out  = (const float*)d_in[10];
    const float* b_out  = (const float*)d_in[11];
    float* out = (float*)d_out;

    const int* src = edge;
    const int* dst = edge + N_EDGES;

    const size_t ND = (size_t)N_NODES * D;

    // workspace layout (16B-aligned by construction)
    unsigned short* hA_hi = (unsigned short*)d_ws;        // ND bf16
    unsigned short* hA_lo = hA_hi + ND;
    unsigned short* hB_hi = hA_lo + ND;
    unsigned short* hB_lo = hB_hi + ND;
    int*   cnt     = (int*)(hB_lo + ND);                  // N
    int*   offsets = cnt + N_NODES;                       // N
    int*   cursor  = offsets + N_NODES;                   // N
    int*   bsums   = cursor + N_NODES;                    // NB (pad to 400)
    unsigned short* wpack = (unsigned short*)(bsums + 400); // 4 x 32768 bf16
    int*   csr     = (int*)(wpack + 4 * 32768);           // E

    // ---- prologue: embed || count || wprep (one launch) ----
    hipMemsetAsync(cnt, 0, N_NODES * sizeof(int), stream);
    k_prep<<<NEMB + NCNT + NWP, 256, 0, stream>>>(
        x, W_emb, b_emb, hA_hi, hA_lo,
        dst, cnt,
        W1_rel, W1_root, W2_rel, W2_root, wpack);

    // ---- scan + fill ----
    k_scan1<<<NB, 256, 0, stream>>>(cnt, offsets, bsums);
    k_scan2<<<1, 512, 0, stream>>>(bsums);
    k_scan3<<<NB, 256, 0, stream>>>(offsets, bsums, cursor);
    k_fill<<<NCNT, 256, 0, stream>>>(src, dst, cursor, csr);

    // ---- conv1 (fused gather + transform) ----
    k_fused<false><<<N_NODES / 32, 512, 0, stream>>>(
        hA_hi, hA_lo, csr, offsets, cnt,
        wpack, wpack + 32768, b1, hB_hi, hB_lo, nullptr, nullptr, nullptr);

    // ---- conv2 + output projection (fused) ----
    k_fused<true><<<N_NODES / 32, 512, 0, stream>>>(
        hB_hi, hB_lo, csr, offsets, cnt,
        wpack + 65536, wpack + 98304, b2, nullptr, nullptr, W_out, b_out, out);
}

// Round 11
// 467.672 us; speedup vs baseline: 1.0117x; 1.0117x over previous
//
#include <hip/hip_runtime.h>
#include <hip/hip_bf16.h>

#define N_NODES 100000
#define N_EDGES 1600000
#define IN_F    32
#define D       128
#define OUT_F   16
#define NB      ((N_NODES + 255) / 256)   // 391 scan blocks
#define NSLICE  8
#define SLICE_NODES (N_NODES / NSLICE)    // 12500

// edge-scan geometry: 16 edges/thread via 4x int4 loads
#define NI4     (N_EDGES / 4)             // 400000 int4s
#define EBLK    ((NI4 + 1023) / 1024)     // 391 blocks per slice-group
#define NCNT    (NSLICE * EBLK)           // 3128 edge-scan blocks

typedef __attribute__((ext_vector_type(8))) short  bf16x8;
typedef __attribute__((ext_vector_type(4))) float  f32x4;

__device__ __forceinline__ unsigned short f2bf(float x) {     // RNE f32 -> bf16 bits
    unsigned u = __float_as_uint(x);
    unsigned r = (u + 0x7FFFu + ((u >> 16) & 1u)) >> 16;
    return (unsigned short)r;
}
__device__ __forceinline__ float bf2f(unsigned short h) {
    return __uint_as_float(((unsigned)h) << 16);
}

// ---------------------------------------------------------------------------
// h0 = x @ W_emb + b_emb  -> split bf16 pair (hi, lo)
// 16 nodes/block, 256 threads = 16 nodes x 16 lanes x 8 cols.
// ---------------------------------------------------------------------------
__global__ __launch_bounds__(256) void k_embed(const float* __restrict__ x,
                                               const float* __restrict__ W,
                                               const float* __restrict__ b,
                                               unsigned short* __restrict__ h_hi,
                                               unsigned short* __restrict__ h_lo) {
    __shared__ float xs[16][IN_F];
    const int base = blockIdx.x * 16;

    if (threadIdx.x < 128) {
        int r = threadIdx.x >> 3, c4 = (threadIdx.x & 7) << 2;
        *reinterpret_cast<float4*>(&xs[r][c4]) =
            *reinterpret_cast<const float4*>(x + (long)(base + r) * IN_F + c4);
    }
    __syncthreads();

    const int nl   = threadIdx.x >> 4;          // node 0..15
    const int col0 = (threadIdx.x & 15) << 3;   // cols col0..col0+7

    float acc[8];
    {
        float4 b0 = *reinterpret_cast<const float4*>(b + col0);
        float4 b1 = *reinterpret_cast<const float4*>(b + col0 + 4);
        acc[0] = b0.x; acc[1] = b0.y; acc[2] = b0.z; acc[3] = b0.w;
        acc[4] = b1.x; acc[5] = b1.y; acc[6] = b1.z; acc[7] = b1.w;
    }
#pragma unroll
    for (int k = 0; k < IN_F; ++k) {
        const float xv = xs[nl][k];
        float4 w0 = *reinterpret_cast<const float4*>(W + k * D + col0);
        float4 w1 = *reinterpret_cast<const float4*>(W + k * D + col0 + 4);
        acc[0] += xv * w0.x; acc[1] += xv * w0.y; acc[2] += xv * w0.z; acc[3] += xv * w0.w;
        acc[4] += xv * w1.x; acc[5] += xv * w1.y; acc[6] += xv * w1.z; acc[7] += xv * w1.w;
    }

    unsigned short hh[8], ll[8];
#pragma unroll
    for (int j = 0; j < 8; ++j) {
        unsigned short h = f2bf(acc[j]);
        hh[j] = h;
        ll[j] = f2bf(acc[j] - bf2f(h));
    }
    long off = (long)(base + nl) * D + col0;
    *reinterpret_cast<bf16x8*>(h_hi + off) = *reinterpret_cast<bf16x8*>(hh);
    *reinterpret_cast<bf16x8*>(h_lo + off) = *reinterpret_cast<bf16x8*>(ll);
}

// ---------------------------------------------------------------------------
// in-degree counts — slice-gated (slice = bid&7 -> one XCD), 4x int4/thread.
// ---------------------------------------------------------------------------
__global__ __launch_bounds__(256) void k_count(const int* __restrict__ dst,
                                               int* __restrict__ cnt) {
    const int slice = blockIdx.x & (NSLICE - 1);
    const int chunk = blockIdx.x >> 3;
    const int lo = slice * SLICE_NODES;
    const int hi = lo + SLICE_NODES;
    const int4* dst4 = reinterpret_cast<const int4*>(dst);
    const int i4base = chunk * 1024;
    const int tid = threadIdx.x;

    int4 d[4];
    bool ok[4];
#pragma unroll
    for (int j = 0; j < 4; ++j) {
        int idx = i4base + j * 256 + tid;
        ok[j] = idx < NI4;
        if (ok[j]) d[j] = dst4[idx];
    }
#pragma unroll
    for (int j = 0; j < 4; ++j) {
        if (ok[j]) {
            if (d[j].x >= lo && d[j].x < hi) atomicAdd(&cnt[d[j].x], 1);
            if (d[j].y >= lo && d[j].y < hi) atomicAdd(&cnt[d[j].y], 1);
            if (d[j].z >= lo && d[j].z < hi) atomicAdd(&cnt[d[j].z], 1);
            if (d[j].w >= lo && d[j].w < hi) atomicAdd(&cnt[d[j].w], 1);
        }
    }
}

// ---------------------------------------------------------------------------
// 3-kernel exclusive prefix scan of cnt[N_NODES] -> offsets (+ cursor copy)
// ---------------------------------------------------------------------------
__global__ __launch_bounds__(256) void k_scan1(const int* __restrict__ cnt,
                                               int* __restrict__ part,
                                               int* __restrict__ blockSums) {
    __shared__ int s[256];
    int i = blockIdx.x * 256 + threadIdx.x;
    int v = (i < N_NODES) ? cnt[i] : 0;
    s[threadIdx.x] = v;
    __syncthreads();
    for (int off = 1; off < 256; off <<= 1) {
        int x = (threadIdx.x >= off) ? s[threadIdx.x - off] : 0;
        __syncthreads();
        s[threadIdx.x] += x;
        __syncthreads();
    }
    if (i < N_NODES) part[i] = s[threadIdx.x] - v;
    if (threadIdx.x == 255) blockSums[blockIdx.x] = s[255];
}

__global__ __launch_bounds__(512) void k_scan2(int* __restrict__ blockSums) {
    __shared__ int s[512];
    int t = threadIdx.x;
    int v = (t < NB) ? blockSums[t] : 0;
    s[t] = v;
    __syncthreads();
    for (int off = 1; off < 512; off <<= 1) {
        int x = (t >= off) ? s[t - off] : 0;
        __syncthreads();
        s[t] += x;
        __syncthreads();
    }
    if (t < NB) blockSums[t] = s[t] - v;
}

__global__ __launch_bounds__(256) void k_scan3(int* __restrict__ offsets,
                                               const int* __restrict__ blockSums,
                                               int* __restrict__ cursor) {
    int i = blockIdx.x * 256 + threadIdx.x;
    if (i < N_NODES) {
        int o = offsets[i] + blockSums[blockIdx.x];
        offsets[i] = o;
        cursor[i]  = o;
    }
}

// ---------------------------------------------------------------------------
// fill CSR: csr[cursor[dst]++] = src — slice-gated, 4x int4 per thread.
// ---------------------------------------------------------------------------
__global__ __launch_bounds__(256) void k_fill(const int* __restrict__ src,
                                              const int* __restrict__ dst,
                                              int* __restrict__ cursor,
                                              int* __restrict__ csr) {
    const int slice = blockIdx.x & (NSLICE - 1);
    const int chunk = blockIdx.x >> 3;
    const int lo = slice * SLICE_NODES;
    const int hi = lo + SLICE_NODES;
    const int4* dst4 = reinterpret_cast<const int4*>(dst);
    const int4* src4 = reinterpret_cast<const int4*>(src);
    const int i4base = chunk * 1024;
    const int tid = threadIdx.x;

    int4 d[4], s[4];
    bool ok[4];
#pragma unroll
    for (int j = 0; j < 4; ++j) {
        int idx = i4base + j * 256 + tid;
        ok[j] = idx < NI4;
        if (ok[j]) { d[j] = dst4[idx]; s[j] = src4[idx]; }
    }
#pragma unroll
    for (int j = 0; j < 4; ++j) {
        if (ok[j]) {
            if (d[j].x >= lo && d[j].x < hi) { int p = atomicAdd(&cursor[d[j].x], 1); csr[p] = s[j].x; }
            if (d[j].y >= lo && d[j].y < hi) { int p = atomicAdd(&cursor[d[j].y], 1); csr[p] = s[j].y; }
            if (d[j].z >= lo && d[j].z < hi) { int p = atomicAdd(&cursor[d[j].z], 1); csr[p] = s[j].z; }
            if (d[j].w >= lo && d[j].w < hi) { int p = atomicAdd(&cursor[d[j].w], 1); csr[p] = s[j].w; }
        }
    }
}

// ---------------------------------------------------------------------------
// Weight prep: split-bf16 pack of Wcat = [Wrel ; Wroot]  (256 x 128, f32)
// into B-fragment layout: pack[(ko*128 + n)*8 + j] = Wcat[ko*8+j][n]
// ---------------------------------------------------------------------------
__global__ __launch_bounds__(256) void k_wprep(const float* __restrict__ W1r,
                                               const float* __restrict__ W1o,
                                               const float* __restrict__ W2r,
                                               const float* __restrict__ W2o,
                                               unsigned short* __restrict__ wp) {
    int c = blockIdx.x * 256 + threadIdx.x;        // 0..8191
    int layer = c >> 12;
    int ko = (c >> 7) & 31;
    int n = c & 127;
    const float* Wrel  = layer ? W2r : W1r;
    const float* Wroot = layer ? W2o : W1o;

    unsigned short hi[8], lo[8];
#pragma unroll
    for (int j = 0; j < 8; ++j) {
        int k = ko * 8 + j;
        float w = (k < D) ? Wrel[k * D + n] : Wroot[(k - D) * D + n];
        unsigned short h = f2bf(w);
        hi[j] = h;
        lo[j] = f2bf(w - bf2f(h));
    }
    unsigned short* base = wp + layer * 65536 + ((ko * 128 + n) << 3);
    *reinterpret_cast<bf16x8*>(base)         = *reinterpret_cast<bf16x8*>(hi);
    *reinterpret_cast<bf16x8*>(base + 32768) = *reinterpret_cast<bf16x8*>(lo);
}

// ---------------------------------------------------------------------------
// Fused RGCN layer, 512 threads / 32 nodes.  (round-9 structure, VGPR 32)
//   gather: one (node, col-chunk) per thread, simple 4-unrolled loop
//   stage : ko 16..31 root copy
//   MFMA  : 8 waves, K=256 split-bf16 (hh, lh, hl)
//   LAST=0: relu + split-write hout(hi/lo)
//   LAST=1: relu -> f32 h in LDS (bank-rotated) -> out = h @ W_out + b_out
// ---------------------------------------------------------------------------
template <bool LAST>
__global__ __launch_bounds__(512) void k_fused(const unsigned short* __restrict__ hin_hi,
                                               const unsigned short* __restrict__ hin_lo,
                                               const int* __restrict__ csr,
                                               const int* __restrict__ offsets,
                                               const int* __restrict__ cnt,
                                               const unsigned short* __restrict__ Wh,
                                               const unsigned short* __restrict__ Wl,
                                               const float* __restrict__ b,
                                               unsigned short* __restrict__ ho_hi,
                                               unsigned short* __restrict__ ho_lo,
                                               const float* __restrict__ Wout,
                                               const float* __restrict__ bout,
                                               float* __restrict__ outp) {
    __shared__ unsigned short Ahi[32 * 32 * 8];   // 16 KB: [ko][row][8] swizzled
    __shared__ unsigned short Alo[32 * 32 * 8];   // 16 KB
    const int base = blockIdx.x * 32;
    const int tid  = threadIdx.x;

    // ---- gather phase: ko = 0..15, one (node,chunk) per thread ----
    {
        const int ko  = tid & 15;
        const int q8  = ko << 3;
        const int row = tid >> 4;                 // 0..31
        const int node = base + row;
        const int beg = offsets[node];
        const int deg = cnt[node];
        const int end = beg + deg;

        float a0[8], a1[8];
#pragma unroll
        for (int j = 0; j < 8; ++j) { a0[j] = 0.f; a1[j] = 0.f; }

        int i = beg;
        for (; i + 3 < end; i += 4) {
            int s0 = csr[i], s1 = csr[i + 1], s2 = csr[i + 2], s3 = csr[i + 3];
            bf16x8 v0 = *reinterpret_cast<const bf16x8*>(hin_hi + (long)s0 * D + q8);
            bf16x8 v1 = *reinterpret_cast<const bf16x8*>(hin_hi + (long)s1 * D + q8);
            bf16x8 v2 = *reinterpret_cast<const bf16x8*>(hin_hi + (long)s2 * D + q8);
            bf16x8 v3 = *reinterpret_cast<const bf16x8*>(hin_hi + (long)s3 * D + q8);
#pragma unroll
            for (int j = 0; j < 8; ++j) {
                a0[j] += bf2f((unsigned short)v0[j]) + bf2f((unsigned short)v1[j]);
                a1[j] += bf2f((unsigned short)v2[j]) + bf2f((unsigned short)v3[j]);
            }
        }
        for (; i < end; ++i) {
            int s0 = csr[i];
            bf16x8 v0 = *reinterpret_cast<const bf16x8*>(hin_hi + (long)s0 * D + q8);
#pragma unroll
            for (int j = 0; j < 8; ++j) a0[j] += bf2f((unsigned short)v0[j]);
        }

        const float sc = 1.f / fmaxf((float)deg, 1.f);
        unsigned short hh[8], ll[8];
#pragma unroll
        for (int j = 0; j < 8; ++j) {
            float v = (a0[j] + a1[j]) * sc;
            unsigned short h = f2bf(v);
            hh[j] = h;
            ll[j] = f2bf(v - bf2f(h));
        }
        const int byteoff = ((ko * 32 + row) * 16) ^ ((ko & 7) << 4);
        *reinterpret_cast<bf16x8*>(reinterpret_cast<char*>(Ahi) + byteoff) =
            *reinterpret_cast<bf16x8*>(hh);
        *reinterpret_cast<bf16x8*>(reinterpret_cast<char*>(Alo) + byteoff) =
            *reinterpret_cast<bf16x8*>(ll);
    }

    // ---- stage root rows: ko = 16..31 (pure copy, pre-split input) ----
    {
        int ko16 = tid & 15;
        int row  = tid >> 4;
        long off = (long)(base + row) * D + ko16 * 8;
        bf16x8 vh = *reinterpret_cast<const bf16x8*>(hin_hi + off);
        bf16x8 vl = *reinterpret_cast<const bf16x8*>(hin_lo + off);
        int ko = 16 + ko16;
        int byteoff = ((ko * 32 + row) * 16) ^ ((ko & 7) << 4);
        *reinterpret_cast<bf16x8*>(reinterpret_cast<char*>(Ahi) + byteoff) = vh;
        *reinterpret_cast<bf16x8*>(reinterpret_cast<char*>(Alo) + byteoff) = vl;
    }
    __syncthreads();

    // ---- MFMA: 8 waves, wave = (mw rows, nwq col-quarter) ----
    const int lane = tid & 63;
    const int wid  = tid >> 6;          // 0..7
    const int mw  = wid & 1;
    const int nwq = wid >> 1;           // 0..3
    const int l15 = lane & 15;
    const int l4  = lane >> 4;

    f32x4 acc[2];
#pragma unroll
    for (int ct = 0; ct < 2; ++ct) acc[ct] = (f32x4){0.f, 0.f, 0.f, 0.f};

    const int arow = mw * 16 + l15;

#pragma unroll
    for (int s = 0; s < 8; ++s) {
        const int ks = s * 4 + l4;
        const int abyte = ((ks * 32 + arow) * 16) ^ ((ks & 7) << 4);
        bf16x8 ah = *reinterpret_cast<const bf16x8*>(
                        reinterpret_cast<const char*>(Ahi) + abyte);
        bf16x8 al = *reinterpret_cast<const bf16x8*>(
                        reinterpret_cast<const char*>(Alo) + abyte);
#pragma unroll
        for (int ct = 0; ct < 2; ++ct) {
            const int colb = nwq * 32 + ct * 16 + l15;
            const long bidx = ((long)(ks * 128 + colb)) << 3;
            bf16x8 bh = *reinterpret_cast<const bf16x8*>(Wh + bidx);
            bf16x8 bl = *reinterpret_cast<const bf16x8*>(Wl + bidx);
            acc[ct] = __builtin_amdgcn_mfma_f32_16x16x32_bf16(ah, bh, acc[ct], 0, 0, 0);
            acc[ct] = __builtin_amdgcn_mfma_f32_16x16x32_bf16(al, bh, acc[ct], 0, 0, 0);
            acc[ct] = __builtin_amdgcn_mfma_f32_16x16x32_bf16(ah, bl, acc[ct], 0, 0, 0);
        }
    }

    if (!LAST) {
        // relu + split-write to global hout
#pragma unroll
        for (int ct = 0; ct < 2; ++ct) {
            const int col = nwq * 32 + ct * 16 + l15;
            const float bv = b[col];
#pragma unroll
            for (int r = 0; r < 4; ++r) {
                long node = base + mw * 16 + l4 * 4 + r;
                float v = fmaxf(acc[ct][r] + bv, 0.f);
                unsigned short h = f2bf(v);
                ho_hi[node * D + col] = h;
                ho_lo[node * D + col] = f2bf(v - bf2f(h));
            }
        }
    } else {
        // relu -> f32 h in LDS (bank-rotated by 4*node) -> projection to OUT
        __syncthreads();                       // all MFMA LDS reads complete
        float* hsm = reinterpret_cast<float*>(Ahi);   // 32 x 128 f32 = 16 KB
#pragma unroll
        for (int ct = 0; ct < 2; ++ct) {
            const int col = nwq * 32 + ct * 16 + l15;
            const float bv = b[col];
#pragma unroll
            for (int r = 0; r < 4; ++r) {
                int nl = mw * 16 + l4 * 4 + r;
                hsm[nl * D + ((col + 4 * nl) & 127)] = fmaxf(acc[ct][r] + bv, 0.f);
            }
        }
        __syncthreads();

        const int nl = tid >> 4;               // node 0..31
        const int oo = tid & 15;               // out col 0..15
        float acc0 = bout[oo];
#pragma unroll 8
        for (int k = 0; k < D; ++k) {
            float hv = hsm[nl * D + ((k + 4 * nl) & 127)];
            acc0 += hv * Wout[k * OUT_F + oo];
        }
        outp[(long)(base + nl) * OUT_F + oo] = acc0;
    }
}

// ---------------------------------------------------------------------------
extern "C" void kernel_launch(void* const* d_in, const int* in_sizes, int n_in,
                              void* d_out, int out_size, void* d_ws, size_t ws_size,
                              hipStream_t stream) {
    const float* x      = (const float*)d_in[0];
    const int*   edge   = (const int*)d_in[1];
    const float* W_emb  = (const float*)d_in[2];
    const float* b_emb  = (const float*)d_in[3];
    const float* W1_rel = (const float*)d_in[4];
    const float* W1_root= (const float*)d_in[5];
    const float* b1     = (const float*)d_in[6];
    const float* W2_rel = (const float*)d_in[7];
    const float* W2_root= (const float*)d_in[8];
    const float* b2     = (const float*)d_in[9];
    const float* W_out  = (const float*)d_in[10];
    const float* b_out  = (const float*)d_in[11];
    float* out = (float*)d_out;

    const int* src = edge;
    const int* dst = edge + N_EDGES;

    const size_t ND = (size_t)N_NODES * D;

    // workspace layout (16B-aligned by construction)
    unsigned short* hA_hi = (unsigned short*)d_ws;        // ND bf16
    unsigned short* hA_lo = hA_hi + ND;
    unsigned short* hB_hi = hA_lo + ND;
    unsigned short* hB_lo = hB_hi + ND;
    int*   cnt     = (int*)(hB_lo + ND);                  // N
    int*   offsets = cnt + N_NODES;                       // N
    int*   cursor  = offsets + N_NODES;                   // N
    int*   bsums   = cursor + N_NODES;                    // NB (pad to 400)
    unsigned short* wpack = (unsigned short*)(bsums + 400); // 4 x 32768 bf16
    int*   csr     = (int*)(wpack + 4 * 32768);           // E

    // ---- CSR build + weight prep ----
    hipMemsetAsync(cnt, 0, N_NODES * sizeof(int), stream);
    k_count<<<NCNT, 256, 0, stream>>>(dst, cnt);
    k_scan1<<<NB, 256, 0, stream>>>(cnt, offsets, bsums);
    k_scan2<<<1, 512, 0, stream>>>(bsums);
    k_scan3<<<NB, 256, 0, stream>>>(offsets, bsums, cursor);
    k_fill<<<NCNT, 256, 0, stream>>>(src, dst, cursor, csr);
    k_wprep<<<32, 256, 0, stream>>>(W1_rel, W1_root, W2_rel, W2_root, wpack);

    // ---- node embed ----
    k_embed<<<N_NODES / 16, 256, 0, stream>>>(x, W_emb, b_emb, hA_hi, hA_lo);

    // ---- conv1 (fused gather + transform) ----
    k_fused<false><<<N_NODES / 32, 512, 0, stream>>>(
        hA_hi, hA_lo, csr, offsets, cnt,
        wpack, wpack + 32768, b1, hB_hi, hB_lo, nullptr, nullptr, nullptr);

    // ---- conv2 + output projection (fused) ----
    k_fused<true><<<N_NODES / 32, 512, 0, stream>>>(
        hB_hi, hB_lo, csr, offsets, cnt,
        wpack + 65536, wpack + 98304, b2, nullptr, nullptr, W_out, b_out, out);
}